// Round 4
// baseline (647.927 us; speedup 1.0000x reference)
//
#include <hip/hip_runtime.h>
#include <hip/hip_bf16.h>

#define BTOK 8192
#define DDIM 1024
#define NEXP 8
#define KCAP 2048
#define HDIM 4096
#define MB ((size_t)1048576)

typedef __attribute__((ext_vector_type(4))) float f32x4;
typedef __attribute__((ext_vector_type(8))) short bf16x8;

__device__ __forceinline__ unsigned short f2bf(float f) {
    union { float f; unsigned u; } v; v.f = f;
    unsigned r = v.u + 0x7fffu + ((v.u >> 16) & 1u);   // RNE
    return (unsigned short)(r >> 16);
}

typedef __attribute__((address_space(3))) unsigned int lds_u32;
typedef __attribute__((address_space(1))) const unsigned int glb_u32;
__device__ __forceinline__ void gl_lds16(const void* g, void* l) {
    __builtin_amdgcn_global_load_lds((glb_u32*)g, (lds_u32*)l, 16, 0, 0);
}

// ---------------- router: gateT[e][b] = softmax(x@Wr + br); also x->bf16 ----------------
__global__ __launch_bounds__(256) void router_kernel(
    const float* __restrict__ x, const float* __restrict__ Wr,
    const float* __restrict__ br, float* __restrict__ gateT,
    unsigned short* __restrict__ xb) {
    __shared__ float wr_s[NEXP][DDIM];
    int t = threadIdx.x;
    for (int i = t; i < NEXP * DDIM; i += 256) {
        int e = i >> 10, d = i & 1023;
        wr_s[e][d] = Wr[d * NEXP + e];
    }
    __syncthreads();
    int wid = t >> 6, lane = t & 63;
    int b = blockIdx.x * 4 + wid;
    const float4* xr = (const float4*)(x + (size_t)b * DDIM);
    float4 xv[4];
#pragma unroll
    for (int j = 0; j < 4; j++) xv[j] = xr[j * 64 + lane];
#pragma unroll
    for (int j = 0; j < 4; j++) {
        short4 s;
        s.x = (short)f2bf(xv[j].x); s.y = (short)f2bf(xv[j].y);
        s.z = (short)f2bf(xv[j].z); s.w = (short)f2bf(xv[j].w);
        *(short4*)(xb + (size_t)b * DDIM + (j * 64 + lane) * 4) = s;
    }
    double acc[NEXP];
#pragma unroll
    for (int e = 0; e < NEXP; e++) {
        double a = 0.0;
#pragma unroll
        for (int j = 0; j < 4; j++) {
            float4 wv = ((const float4*)&wr_s[e][0])[j * 64 + lane];
            a += (double)xv[j].x * wv.x + (double)xv[j].y * wv.y
               + (double)xv[j].z * wv.z + (double)xv[j].w * wv.w;
        }
#pragma unroll
        for (int s = 1; s < 64; s <<= 1) a += __shfl_xor(a, s, 64);
        acc[e] = a + (double)br[e];
    }
    if (lane == 0) {
        double mx = acc[0];
#pragma unroll
        for (int e = 1; e < NEXP; e++) mx = fmax(mx, acc[e]);
        double p[NEXP]; double ssum = 0.0;
#pragma unroll
        for (int e = 0; e < NEXP; e++) { p[e] = exp(acc[e] - mx); ssum += p[e]; }
        double inv = 1.0 / ssum;
#pragma unroll
        for (int e = 0; e < NEXP; e++) gateT[e * BTOK + b] = (float)(p[e] * inv);
    }
}

// ---------------- radix select: K-th largest per expert ----------------
__global__ __launch_bounds__(256) void select_kernel(
    const float* __restrict__ gateT, unsigned* __restrict__ meta) {
    int e = blockIdx.x, t = threadIdx.x;
    const float* g = gateT + e * BTOK;
    __shared__ unsigned hist[256];
    __shared__ unsigned sh_prefix;
    __shared__ int sh_rem;
    if (t == 0) { sh_prefix = 0; sh_rem = KCAP; }
    __syncthreads();
    for (int pass = 0; pass < 4; pass++) {
        int shift = 24 - pass * 8;
        hist[t] = 0;
        __syncthreads();
        unsigned pfx = sh_prefix;
        for (int i = t; i < BTOK; i += 256) {
            unsigned key = __float_as_uint(g[i]);
            if (pass == 0 || (key >> (shift + 8)) == pfx)
                atomicAdd(&hist[(key >> shift) & 255u], 1u);
        }
        __syncthreads();
        if (t == 0) {
            int rem = sh_rem, cum = 0, d = 0;
            for (int dd = 255; dd >= 0; dd--) {
                cum += (int)hist[dd];
                if (cum >= rem) { d = dd; break; }
            }
            sh_rem = rem - (cum - (int)hist[d]);
            sh_prefix = (pfx << 8) | (unsigned)d;
        }
        __syncthreads();
    }
    unsigned cutoff = sh_prefix;
    int cnt = 0;
    for (int i = t; i < BTOK; i += 256)
        if (__float_as_uint(g[i]) > cutoff) cnt++;
    __shared__ int red[256];
    red[t] = cnt; __syncthreads();
    for (int s = 128; s > 0; s >>= 1) { if (t < s) red[t] += red[t + s]; __syncthreads(); }
    if (t == 0) { meta[e] = cutoff; meta[NEXP + e] = (unsigned)red[0]; }
}

// ---------------- build: strictly-above-cutoff tokens ----------------
__global__ __launch_bounds__(256) void build_kernel(
    const float* __restrict__ gateT, const unsigned* __restrict__ meta,
    unsigned* __restrict__ cnt, int* __restrict__ idx_list, float* __restrict__ wt_list) {
    int e = blockIdx.y;
    int b = blockIdx.x * 256 + threadIdx.x;
    float gv = gateT[(size_t)e * BTOK + b];
    if (__float_as_uint(gv) > meta[e]) {
        unsigned pos = atomicAdd(&cnt[e], 1u);
        if (pos < KCAP) {
            idx_list[(size_t)e * KCAP + pos] = b;
            wt_list[(size_t)e * KCAP + pos] = gv;
        }
    }
}

// ---------------- ties: cooperative prefix scan, lowest index first ----------------
__global__ __launch_bounds__(256) void tie_kernel(
    const float* __restrict__ gateT, const unsigned* __restrict__ meta,
    unsigned* __restrict__ cnt, int* __restrict__ idx_list, float* __restrict__ wt_list) {
    int e = blockIdx.x, t = threadIdx.x;
    unsigned cutoff = meta[e];
    int need = KCAP - (int)meta[NEXP + e];
    const float* g = gateT + (size_t)e * BTOK;
    __shared__ int pre[256];
    int base = t * 32;
    int c = 0;
    for (int j = 0; j < 32; j++) c += (__float_as_uint(g[base + j]) == cutoff) ? 1 : 0;
    pre[t] = c;
    __syncthreads();
    for (int s = 1; s < 256; s <<= 1) {
        int v = (t >= s) ? pre[t - s] : 0;
        __syncthreads();
        pre[t] += v;
        __syncthreads();
    }
    int rank = pre[t] - c;   // exclusive prefix of tie count
    for (int j = 0; j < 32; j++) {
        float gv = g[base + j];
        if (__float_as_uint(gv) == cutoff) {
            if (rank < need) {
                unsigned pos = atomicAdd(&cnt[e], 1u);
                if (pos < KCAP) {
                    idx_list[(size_t)e * KCAP + pos] = base + j;
                    wt_list[(size_t)e * KCAP + pos] = gv;
                }
            }
            rank++;
        }
    }
}

// ---------------- inverse map: inv[e][token] = slot ----------------
__global__ __launch_bounds__(256) void invb_kernel(
    const int* __restrict__ idx_list, int* __restrict__ inv) {
    int i = blockIdx.x * 256 + threadIdx.x;
    int e = i >> 11, slot = i & (KCAP - 1);
    inv[(size_t)e * BTOK + idx_list[i]] = slot;
}

// ---------------- transpose+convert: src[R][C] f32 -> dst[C][R] bf16 (per z) ----------------
__global__ __launch_bounds__(256) void tcvt_kernel(
    const float* __restrict__ src, unsigned short* __restrict__ dst, int R, int C) {
    size_t zoff = (size_t)blockIdx.z * R * C;
    src += zoff; dst += zoff;
    __shared__ unsigned short tile[64][72];
    int c0 = blockIdx.x * 64, r0 = blockIdx.y * 64;
    int t = threadIdx.x;
    int cq = t & 15, rr = t >> 4;
#pragma unroll
    for (int ri = 0; ri < 4; ri++) {
        int r = ri * 16 + rr;
        float4 v = *(const float4*)(src + (size_t)(r0 + r) * C + c0 + cq * 4);
        tile[cq * 4 + 0][r] = f2bf(v.x);
        tile[cq * 4 + 1][r] = f2bf(v.y);
        tile[cq * 4 + 2][r] = f2bf(v.z);
        tile[cq * 4 + 3][r] = f2bf(v.w);
    }
    __syncthreads();
    int rq = t & 15, cc = t >> 4;
#pragma unroll
    for (int ci = 0; ci < 4; ci++) {
        int c = ci * 16 + cc;
        *(short4*)(dst + (size_t)(c0 + c) * R + r0 + rq * 4) = *(const short4*)&tile[c][rq * 4];
    }
}

// ============ 256x256 GEMMs: 8 waves, BK=32, 4-slot LDS ring, counted vmcnt ============
// Both operands are k-contiguous bf16 rows. Per K-tile (32 k): iter t stages tile t+3
// into ring slot (t+3)&3 (its last reader finished before the previous barrier), reads
// slot t&3, 32 MFMAs under setprio, then vmcnt(8) + one raw s_barrier. Swizzle: quad
// XOR ((row>>1)&3)<<4, applied on the pre-swizzled global source (gl_lds writes
// linearly) and on ds_read.

#define RSLOT (256 * 32)   // ushorts per ring slot (32 KB)

// gemm1: h[e][m][n] = relu(xb[toks[e][m]] @ w1t[e][n] + b1[e][n]);  z = expert
__global__ __launch_bounds__(512, 2) void gemm1_kernel(
    const unsigned short* __restrict__ xb, const unsigned short* __restrict__ w1t,
    const float* __restrict__ b1, const int* __restrict__ idx_list,
    unsigned short* __restrict__ h) {
    int e = blockIdx.z;
    w1t      += (size_t)e * DDIM * HDIM;
    b1       += (size_t)e * HDIM;
    idx_list += (size_t)e * KCAP;
    h        += (size_t)e * KCAP * HDIM;
    __shared__ unsigned short As[4 * RSLOT];
    __shared__ unsigned short Bs[4 * RSLOT];
    __shared__ int toks[256];
    int t = threadIdx.x;
    int m0 = blockIdx.x * 256, n0 = blockIdx.y * 256;
    if (t < 256) toks[t] = idx_list[m0 + t];
    __syncthreads();
    int w = t >> 6, lane = t & 63;
    int l2 = lane >> 2;
    unsigned swq = (unsigned)(((lane & 3) ^ ((lane >> 3) & 3)) << 4);
    const char* pa0 = (const char*)(xb + (size_t)toks[w * 16 + l2] * DDIM) + swq;
    const char* pa1 = (const char*)(xb + (size_t)toks[128 + w * 16 + l2] * DDIM) + swq;
    const char* pb0 = (const char*)(w1t + (size_t)(n0 + w * 16 + l2) * DDIM) + swq;
    const char* pb1 = (const char*)(w1t + (size_t)(n0 + 128 + w * 16 + l2) * DDIM) + swq;
    unsigned short* da0 = As + (w * 16) * 32;
    unsigned short* da1 = As + (128 + w * 16) * 32;
    unsigned short* db0 = Bs + (w * 16) * 32;
    unsigned short* db1 = Bs + (128 + w * 16) * 32;
#define STAGE1(slot, tt) do { size_t ko = (size_t)(tt) * 64; int so = (slot) * RSLOT; \
    gl_lds16(pa0 + ko, da0 + so); gl_lds16(pa1 + ko, da1 + so);                        \
    gl_lds16(pb0 + ko, db0 + so); gl_lds16(pb1 + ko, db1 + so); } while (0)
    int wm = w >> 2, wn = w & 3;
    int fr = lane & 15, kg = lane >> 4;
    unsigned koffr = (unsigned)((kg ^ ((fr >> 1) & 3)) << 4);
    const int NT = DDIM / 32;
    f32x4 acc[8][4] = {};
    STAGE1(0, 0); STAGE1(1, 1); STAGE1(2, 2);
    asm volatile("s_waitcnt vmcnt(8)" ::: "memory");
    __builtin_amdgcn_s_barrier();
    for (int kt = 0; kt < NT; kt++) {
        if (kt + 3 < NT) STAGE1((kt + 3) & 3, kt + 3);
        const char* ab = (const char*)(As + (kt & 3) * RSLOT);
        const char* bb = (const char*)(Bs + (kt & 3) * RSLOT);
        bf16x8 af[8], bf[4];
#pragma unroll
        for (int mf = 0; mf < 8; mf++)
            af[mf] = *(const bf16x8*)(ab + (wm * 128 + mf * 16 + fr) * 64 + koffr);
#pragma unroll
        for (int nf = 0; nf < 4; nf++)
            bf[nf] = *(const bf16x8*)(bb + (wn * 64 + nf * 16 + fr) * 64 + koffr);
        __builtin_amdgcn_s_setprio(1);
#pragma unroll
        for (int mf = 0; mf < 8; mf++)
#pragma unroll
            for (int nf = 0; nf < 4; nf++)
                acc[mf][nf] = __builtin_amdgcn_mfma_f32_16x16x32_bf16(
                    af[mf], bf[nf], acc[mf][nf], 0, 0, 0);
        __builtin_amdgcn_s_setprio(0);
        if (kt + 1 < NT) {
            int rem = NT - 2 - kt;   // staged tiles newer than kt+1
            if (rem >= 2)      asm volatile("s_waitcnt vmcnt(8)" ::: "memory");
            else if (rem == 1) asm volatile("s_waitcnt vmcnt(4)" ::: "memory");
            else               asm volatile("s_waitcnt vmcnt(0)" ::: "memory");
            __builtin_amdgcn_s_barrier();
        }
    }
#undef STAGE1
    int hi = lane >> 4;
#pragma unroll
    for (int nf = 0; nf < 4; nf++) {
        int col = n0 + wn * 64 + nf * 16 + fr;
        float bias = b1[col];
#pragma unroll
        for (int mf = 0; mf < 8; mf++) {
            int r0 = wm * 128 + mf * 16 + hi * 4;
#pragma unroll
            for (int r = 0; r < 4; r++) {
                float v = fmaxf(acc[mf][nf][r] + bias, 0.f);
                h[(size_t)(m0 + r0 + r) * HDIM + col] = f2bf(v);
            }
        }
    }
}

// gemm2y: yb[e][m][n] = wt[e][m] * (h[e][m] @ w2t[e][n] + b2[e][n]);  z = expert
__global__ __launch_bounds__(512, 2) void gemm2y_kernel(
    const unsigned short* __restrict__ h, const unsigned short* __restrict__ w2t,
    const float* __restrict__ b2, const float* __restrict__ wt_list,
    float* __restrict__ yb) {
    int e = blockIdx.z;
    h       += (size_t)e * KCAP * HDIM;
    w2t     += (size_t)e * DDIM * HDIM;
    b2      += (size_t)e * DDIM;
    wt_list += (size_t)e * KCAP;
    yb      += (size_t)e * KCAP * DDIM;
    __shared__ unsigned short As[4 * RSLOT];
    __shared__ unsigned short Bs[4 * RSLOT];
    __shared__ float wts[256];
    int t = threadIdx.x;
    int m0 = blockIdx.x * 256, n0 = blockIdx.y * 256;
    if (t < 256) wts[t] = wt_list[m0 + t];
    __syncthreads();
    int w = t >> 6, lane = t & 63;
    int l2 = lane >> 2;
    unsigned swq = (unsigned)(((lane & 3) ^ ((lane >> 3) & 3)) << 4);
    const char* pa0 = (const char*)(h + (size_t)(m0 + w * 16 + l2) * HDIM) + swq;
    const char* pa1 = (const char*)(h + (size_t)(m0 + 128 + w * 16 + l2) * HDIM) + swq;
    const char* pb0 = (const char*)(w2t + (size_t)(n0 + w * 16 + l2) * HDIM) + swq;
    const char* pb1 = (const char*)(w2t + (size_t)(n0 + 128 + w * 16 + l2) * HDIM) + swq;
    unsigned short* da0 = As + (w * 16) * 32;
    unsigned short* da1 = As + (128 + w * 16) * 32;
    unsigned short* db0 = Bs + (w * 16) * 32;
    unsigned short* db1 = Bs + (128 + w * 16) * 32;
#define STAGE2(slot, tt) do { size_t ko = (size_t)(tt) * 64; int so = (slot) * RSLOT; \
    gl_lds16(pa0 + ko, da0 + so); gl_lds16(pa1 + ko, da1 + so);                        \
    gl_lds16(pb0 + ko, db0 + so); gl_lds16(pb1 + ko, db1 + so); } while (0)
    int wm = w >> 2, wn = w & 3;
    int fr = lane & 15, kg = lane >> 4;
    unsigned koffr = (unsigned)((kg ^ ((fr >> 1) & 3)) << 4);
    const int NT = HDIM / 32;
    f32x4 acc[8][4] = {};
    STAGE2(0, 0); STAGE2(1, 1); STAGE2(2, 2);
    asm volatile("s_waitcnt vmcnt(8)" ::: "memory");
    __builtin_amdgcn_s_barrier();
    for (int kt = 0; kt < NT; kt++) {
        if (kt + 3 < NT) STAGE2((kt + 3) & 3, kt + 3);
        const char* ab = (const char*)(As + (kt & 3) * RSLOT);
        const char* bb = (const char*)(Bs + (kt & 3) * RSLOT);
        bf16x8 af[8], bf[4];
#pragma unroll
        for (int mf = 0; mf < 8; mf++)
            af[mf] = *(const bf16x8*)(ab + (wm * 128 + mf * 16 + fr) * 64 + koffr);
#pragma unroll
        for (int nf = 0; nf < 4; nf++)
            bf[nf] = *(const bf16x8*)(bb + (wn * 64 + nf * 16 + fr) * 64 + koffr);
        __builtin_amdgcn_s_setprio(1);
#pragma unroll
        for (int mf = 0; mf < 8; mf++)
#pragma unroll
            for (int nf = 0; nf < 4; nf++)
                acc[mf][nf] = __builtin_amdgcn_mfma_f32_16x16x32_bf16(
                    af[mf], bf[nf], acc[mf][nf], 0, 0, 0);
        __builtin_amdgcn_s_setprio(0);
        if (kt + 1 < NT) {
            int rem = NT - 2 - kt;
            if (rem >= 2)      asm volatile("s_waitcnt vmcnt(8)" ::: "memory");
            else if (rem == 1) asm volatile("s_waitcnt vmcnt(4)" ::: "memory");
            else               asm volatile("s_waitcnt vmcnt(0)" ::: "memory");
            __builtin_amdgcn_s_barrier();
        }
    }
#undef STAGE2
    int hi = lane >> 4;
#pragma unroll
    for (int nf = 0; nf < 4; nf++) {
        int col = n0 + wn * 64 + nf * 16 + fr;
        float bias = b2[col];
#pragma unroll
        for (int mf = 0; mf < 8; mf++) {
            int r0 = wm * 128 + mf * 16 + hi * 4;
#pragma unroll
            for (int r = 0; r < 4; r++) {
                int lrow = r0 + r;
                yb[(size_t)(m0 + lrow) * DDIM + col] = wts[lrow] * (acc[mf][nf][r] + bias);
            }
        }
    }
}

// ---------------- combine: out[b] = sum_e yb[e][inv[e][b]] ----------------
__global__ __launch_bounds__(256) void combine_kernel(
    const float* __restrict__ yb, const int* __restrict__ inv,
    float* __restrict__ out) {
    int b = blockIdx.x, t = threadIdx.x;
    float4 acc = {0.f, 0.f, 0.f, 0.f};
#pragma unroll
    for (int e = 0; e < NEXP; e++) {
        int s = inv[(size_t)e * BTOK + b];
        if (s >= 0) {
            float4 v = *(const float4*)(yb + ((size_t)e * KCAP + s) * DDIM + t * 4);
            acc.x += v.x; acc.y += v.y; acc.z += v.z; acc.w += v.w;
        }
    }
    *(float4*)(out + (size_t)b * DDIM + t * 4) = acc;
}

extern "C" void kernel_launch(void* const* d_in, const int* in_sizes, int n_in,
                              void* d_out, int out_size, void* d_ws, size_t ws_size,
                              hipStream_t stream) {
    const float* x  = (const float*)d_in[0];
    const float* Wr = (const float*)d_in[1];
    const float* br = (const float*)d_in[2];
    const float* W1 = (const float*)d_in[3];
    const float* b1 = (const float*)d_in[4];
    const float* W2 = (const float*)d_in[5];
    const float* b2 = (const float*)d_in[6];
    float* out = (float*)d_out;

    char* ws = (char*)d_ws;
    float*    gateT    = (float*)ws;                       // 256 KB
    unsigned* meta     = (unsigned*)(ws + 262144);         // cutoff[8], ngt[8]
    unsigned* cnt      = meta + 16;
    int*      idx_list = (int*)(ws + 327680);              // 64 KB
    float*    wt_list  = (float*)(ws + 393216);            // 64 KB
    int*      inv      = (int*)(ws + 458752);              // 256 KB
    unsigned short* xbuf = (unsigned short*)(ws + 1 * MB); // 16 MB
    unsigned short* w1t  = (unsigned short*)(ws + 17 * MB);   // 64 MB
    unsigned short* w2t  = (unsigned short*)(ws + 81 * MB);   // 64 MB
    unsigned short* hbuf = (unsigned short*)(ws + 145 * MB);  // 128 MB
    float*          yb   = (float*)(ws + 273 * MB);           // 64 MB
    const size_t NEED = 337 * MB;
    if (ws_size < NEED) return;

    hipMemsetAsync(cnt, 0, NEXP * sizeof(unsigned), stream);
    hipMemsetAsync(inv, 0xFF, (size_t)NEXP * BTOK * sizeof(int), stream);

    router_kernel<<<dim3(BTOK / 4), 256, 0, stream>>>(x, Wr, br, gateT, xbuf);
    select_kernel<<<dim3(NEXP), 256, 0, stream>>>(gateT, meta);
    build_kernel<<<dim3(BTOK / 256, NEXP), 256, 0, stream>>>(gateT, meta, cnt, idx_list, wt_list);
    tie_kernel<<<dim3(NEXP), 256, 0, stream>>>(gateT, meta, cnt, idx_list, wt_list);

    tcvt_kernel<<<dim3(HDIM / 64, DDIM / 64, NEXP), 256, 0, stream>>>(W1, w1t, DDIM, HDIM);
    tcvt_kernel<<<dim3(DDIM / 64, HDIM / 64, NEXP), 256, 0, stream>>>(W2, w2t, HDIM, DDIM);
    invb_kernel<<<dim3(NEXP * KCAP / 256), 256, 0, stream>>>(idx_list, inv);

    gemm1_kernel<<<dim3(KCAP / 256, HDIM / 256, NEXP), 512, 0, stream>>>(
        xbuf, w1t, b1, idx_list, hbuf);
    gemm2y_kernel<<<dim3(KCAP / 256, DDIM / 256, NEXP), 512, 0, stream>>>(
        hbuf, w2t, b2, wt_list, yb);
    combine_kernel<<<dim3(BTOK), 256, 0, stream>>>(yb, inv, out);
}

// Round 5
// 567.499 us; speedup vs baseline: 1.1417x; 1.1417x over previous
//
#include <hip/hip_runtime.h>
#include <hip/hip_bf16.h>

#define BTOK 8192
#define DDIM 1024
#define NEXP 8
#define KCAP 2048
#define HDIM 4096
#define MB ((size_t)1048576)

typedef __attribute__((ext_vector_type(4))) float f32x4;
typedef __attribute__((ext_vector_type(8))) short bf16x8;

__device__ __forceinline__ unsigned short f2bf(float f) {
    union { float f; unsigned u; } v; v.f = f;
    unsigned r = v.u + 0x7fffu + ((v.u >> 16) & 1u);   // RNE
    return (unsigned short)(r >> 16);
}

typedef __attribute__((address_space(3))) unsigned int lds_u32;
typedef __attribute__((address_space(1))) const unsigned int glb_u32;
__device__ __forceinline__ void gl_lds16(const void* g, void* l) {
    __builtin_amdgcn_global_load_lds((glb_u32*)g, (lds_u32*)l, 16, 0, 0);
}

// ---------------- router: gateT[e][b] = softmax(x@Wr + br); also x->bf16 ----------------
__global__ __launch_bounds__(256) void router_kernel(
    const float* __restrict__ x, const float* __restrict__ Wr,
    const float* __restrict__ br, float* __restrict__ gateT,
    unsigned short* __restrict__ xb) {
    __shared__ float wr_s[NEXP][DDIM];
    int t = threadIdx.x;
    for (int i = t; i < NEXP * DDIM; i += 256) {
        int e = i >> 10, d = i & 1023;
        wr_s[e][d] = Wr[d * NEXP + e];
    }
    __syncthreads();
    int wid = t >> 6, lane = t & 63;
    int b = blockIdx.x * 4 + wid;
    const float4* xr = (const float4*)(x + (size_t)b * DDIM);
    float4 xv[4];
#pragma unroll
    for (int j = 0; j < 4; j++) xv[j] = xr[j * 64 + lane];
#pragma unroll
    for (int j = 0; j < 4; j++) {
        short4 s;
        s.x = (short)f2bf(xv[j].x); s.y = (short)f2bf(xv[j].y);
        s.z = (short)f2bf(xv[j].z); s.w = (short)f2bf(xv[j].w);
        *(short4*)(xb + (size_t)b * DDIM + (j * 64 + lane) * 4) = s;
    }
    double acc[NEXP];
#pragma unroll
    for (int e = 0; e < NEXP; e++) {
        double a = 0.0;
#pragma unroll
        for (int j = 0; j < 4; j++) {
            float4 wv = ((const float4*)&wr_s[e][0])[j * 64 + lane];
            a += (double)xv[j].x * wv.x + (double)xv[j].y * wv.y
               + (double)xv[j].z * wv.z + (double)xv[j].w * wv.w;
        }
#pragma unroll
        for (int s = 1; s < 64; s <<= 1) a += __shfl_xor(a, s, 64);
        acc[e] = a + (double)br[e];
    }
    if (lane == 0) {
        double mx = acc[0];
#pragma unroll
        for (int e = 1; e < NEXP; e++) mx = fmax(mx, acc[e]);
        double p[NEXP]; double ssum = 0.0;
#pragma unroll
        for (int e = 0; e < NEXP; e++) { p[e] = exp(acc[e] - mx); ssum += p[e]; }
        double inv = 1.0 / ssum;
#pragma unroll
        for (int e = 0; e < NEXP; e++) gateT[e * BTOK + b] = (float)(p[e] * inv);
    }
}

// ---------------- radix select: K-th largest per expert ----------------
__global__ __launch_bounds__(256) void select_kernel(
    const float* __restrict__ gateT, unsigned* __restrict__ meta) {
    int e = blockIdx.x, t = threadIdx.x;
    const float* g = gateT + e * BTOK;
    __shared__ unsigned hist[256];
    __shared__ unsigned sh_prefix;
    __shared__ int sh_rem;
    if (t == 0) { sh_prefix = 0; sh_rem = KCAP; }
    __syncthreads();
    for (int pass = 0; pass < 4; pass++) {
        int shift = 24 - pass * 8;
        hist[t] = 0;
        __syncthreads();
        unsigned pfx = sh_prefix;
        for (int i = t; i < BTOK; i += 256) {
            unsigned key = __float_as_uint(g[i]);
            if (pass == 0 || (key >> (shift + 8)) == pfx)
                atomicAdd(&hist[(key >> shift) & 255u], 1u);
        }
        __syncthreads();
        if (t == 0) {
            int rem = sh_rem, cum = 0, d = 0;
            for (int dd = 255; dd >= 0; dd--) {
                cum += (int)hist[dd];
                if (cum >= rem) { d = dd; break; }
            }
            sh_rem = rem - (cum - (int)hist[d]);
            sh_prefix = (pfx << 8) | (unsigned)d;
        }
        __syncthreads();
    }
    unsigned cutoff = sh_prefix;
    int cnt = 0;
    for (int i = t; i < BTOK; i += 256)
        if (__float_as_uint(g[i]) > cutoff) cnt++;
    __shared__ int red[256];
    red[t] = cnt; __syncthreads();
    for (int s = 128; s > 0; s >>= 1) { if (t < s) red[t] += red[t + s]; __syncthreads(); }
    if (t == 0) { meta[e] = cutoff; meta[NEXP + e] = (unsigned)red[0]; }
}

// ---------------- build: strictly-above-cutoff tokens ----------------
__global__ __launch_bounds__(256) void build_kernel(
    const float* __restrict__ gateT, const unsigned* __restrict__ meta,
    unsigned* __restrict__ cnt, int* __restrict__ idx_list, float* __restrict__ wt_list) {
    int e = blockIdx.y;
    int b = blockIdx.x * 256 + threadIdx.x;
    float gv = gateT[(size_t)e * BTOK + b];
    if (__float_as_uint(gv) > meta[e]) {
        unsigned pos = atomicAdd(&cnt[e], 1u);
        if (pos < KCAP) {
            idx_list[(size_t)e * KCAP + pos] = b;
            wt_list[(size_t)e * KCAP + pos] = gv;
        }
    }
}

// ---------------- ties: cooperative prefix scan, lowest index first ----------------
__global__ __launch_bounds__(256) void tie_kernel(
    const float* __restrict__ gateT, const unsigned* __restrict__ meta,
    unsigned* __restrict__ cnt, int* __restrict__ idx_list, float* __restrict__ wt_list) {
    int e = blockIdx.x, t = threadIdx.x;
    unsigned cutoff = meta[e];
    int need = KCAP - (int)meta[NEXP + e];
    const float* g = gateT + (size_t)e * BTOK;
    __shared__ int pre[256];
    int base = t * 32;
    int c = 0;
    for (int j = 0; j < 32; j++) c += (__float_as_uint(g[base + j]) == cutoff) ? 1 : 0;
    pre[t] = c;
    __syncthreads();
    for (int s = 1; s < 256; s <<= 1) {
        int v = (t >= s) ? pre[t - s] : 0;
        __syncthreads();
        pre[t] += v;
        __syncthreads();
    }
    int rank = pre[t] - c;   // exclusive prefix of tie count
    for (int j = 0; j < 32; j++) {
        float gv = g[base + j];
        if (__float_as_uint(gv) == cutoff) {
            if (rank < need) {
                unsigned pos = atomicAdd(&cnt[e], 1u);
                if (pos < KCAP) {
                    idx_list[(size_t)e * KCAP + pos] = base + j;
                    wt_list[(size_t)e * KCAP + pos] = gv;
                }
            }
            rank++;
        }
    }
}

// ---------------- inverse map: inv[e][token] = slot ----------------
__global__ __launch_bounds__(256) void invb_kernel(
    const int* __restrict__ idx_list, int* __restrict__ inv) {
    int i = blockIdx.x * 256 + threadIdx.x;
    int e = i >> 11, slot = i & (KCAP - 1);
    inv[(size_t)e * BTOK + idx_list[i]] = slot;
}

// ---------------- transpose+convert: src[R][C] f32 -> dst[C][R] bf16 (per z) ----------------
__global__ __launch_bounds__(256) void tcvt_kernel(
    const float* __restrict__ src, unsigned short* __restrict__ dst, int R, int C) {
    size_t zoff = (size_t)blockIdx.z * R * C;
    src += zoff; dst += zoff;
    __shared__ unsigned short tile[64][72];
    int c0 = blockIdx.x * 64, r0 = blockIdx.y * 64;
    int t = threadIdx.x;
    int cq = t & 15, rr = t >> 4;
#pragma unroll
    for (int ri = 0; ri < 4; ri++) {
        int r = ri * 16 + rr;
        float4 v = *(const float4*)(src + (size_t)(r0 + r) * C + c0 + cq * 4);
        tile[cq * 4 + 0][r] = f2bf(v.x);
        tile[cq * 4 + 1][r] = f2bf(v.y);
        tile[cq * 4 + 2][r] = f2bf(v.z);
        tile[cq * 4 + 3][r] = f2bf(v.w);
    }
    __syncthreads();
    int rq = t & 15, cc = t >> 4;
#pragma unroll
    for (int ci = 0; ci < 4; ci++) {
        int c = ci * 16 + cc;
        *(short4*)(dst + (size_t)(c0 + c) * R + r0 + rq * 4) = *(const short4*)&tile[c][rq * 4];
    }
}

// ============ 128x256 GEMMs: 8 waves (64x64/wave), BK=32, 3-slot LDS ring ============
// 2 blocks/CU (74 KB LDS, ~110 VGPR) for cross-block TLP + counted vmcnt prefetch-2.
// Per iter: stage tile kt+2 into slot (kt+2)%3 (3 gl_lds16/thread), read slot kt%3
// (8 ds_read_b128/wave), 16 MFMA under setprio, vmcnt(3) (never 0 mid-loop), barrier.
// Race-freedom: slot s written at iter kt was last read at iter kt-1 (reads complete
// before that iter's barrier); writes complete before reads at kt+2 via the vmcnt(3)
// at end of iter kt+1 (forces all but the newest stage to retire).
// Swizzle (rule #21, both-sides): global chunk pre-swizzled ((lane&3)^((lane>>3)&3))<<4,
// ds_read chunk (kg^((fr>>1)&3))<<4 — same involution, verified r4.
// Grid: 1D, expert = bid&7 -> each expert pinned to one XCD (T1 L2 locality).

#define ASLOT 4096   // ushorts per A slot (128 rows x 32)
#define BSLOT 8192   // ushorts per B slot (256 rows x 32)

// gemm1: h[e][m][n] = relu(xb[toks[e][m]] @ w1t[e][n] + b1[e][n])
__global__ __launch_bounds__(512, 4) void gemm1_kernel(
    const unsigned short* __restrict__ xb, const unsigned short* __restrict__ w1t,
    const float* __restrict__ b1, const int* __restrict__ idx_list,
    unsigned short* __restrict__ h) {
    int bid = blockIdx.x;
    int e = bid & 7, idx = bid >> 3;          // 256 blocks per expert/XCD
    int m0 = (idx & 15) * 128, n0 = (idx >> 4) * 256;
    w1t      += (size_t)e * DDIM * HDIM;
    b1       += (size_t)e * HDIM;
    idx_list += (size_t)e * KCAP;
    h        += (size_t)e * KCAP * HDIM;
    __shared__ unsigned short As[3 * ASLOT];
    __shared__ unsigned short Bs[3 * BSLOT];
    __shared__ int toks[128];
    int t = threadIdx.x;
    if (t < 128) toks[t] = idx_list[m0 + t];
    __syncthreads();
    int w = t >> 6, lane = t & 63, l4 = lane >> 2;
    unsigned swz = (unsigned)(((lane & 3) ^ ((lane >> 3) & 3)) << 4);
    const char* pa  = (const char*)(xb + (size_t)toks[w * 16 + l4] * DDIM) + swz;
    const char* pb0 = (const char*)(w1t + (size_t)(n0 + w * 16 + l4) * DDIM) + swz;
    const char* pb1 = (const char*)(w1t + (size_t)(n0 + 128 + w * 16 + l4) * DDIM) + swz;
    unsigned short* da  = As + (w * 16) * 32;          // wave-uniform dests
    unsigned short* db0 = Bs + (w * 16) * 32;
    unsigned short* db1 = Bs + (128 + w * 16) * 32;
#define ST1(slot, koff) do {                                         \
    gl_lds16(pa  + (koff), da  + (slot) * ASLOT);                    \
    gl_lds16(pb0 + (koff), db0 + (slot) * BSLOT);                    \
    gl_lds16(pb1 + (koff), db1 + (slot) * BSLOT); } while (0)
    int wm = w >> 2, wn = w & 3;
    int fr = lane & 15, kg = lane >> 4;
    unsigned koffr = (unsigned)((kg ^ ((fr >> 1) & 3)) << 4);
    const int NT = DDIM / 32;   // 32
    f32x4 acc[4][4] = {};
    ST1(0, 0); ST1(1, 64);
    asm volatile("s_waitcnt vmcnt(3)" ::: "memory");
    __builtin_amdgcn_s_barrier();
    size_t ko = 128;
    int sw = 2, sr = 0;
    for (int kt = 0; kt < NT; kt++) {
        if (kt + 2 < NT) { ST1(sw, ko); ko += 64; }
        const char* ab = (const char*)As + sr * (ASLOT * 2);
        const char* bb = (const char*)Bs + sr * (BSLOT * 2);
        bf16x8 af[4], bf[4];
#pragma unroll
        for (int mf = 0; mf < 4; mf++)
            af[mf] = *(const bf16x8*)(ab + (wm * 64 + mf * 16 + fr) * 64 + koffr);
#pragma unroll
        for (int nf = 0; nf < 4; nf++)
            bf[nf] = *(const bf16x8*)(bb + (wn * 64 + nf * 16 + fr) * 64 + koffr);
        __builtin_amdgcn_s_setprio(1);
#pragma unroll
        for (int mf = 0; mf < 4; mf++)
#pragma unroll
            for (int nf = 0; nf < 4; nf++)
                acc[mf][nf] = __builtin_amdgcn_mfma_f32_16x16x32_bf16(
                    af[mf], bf[nf], acc[mf][nf], 0, 0, 0);
        __builtin_amdgcn_s_setprio(0);
        if (kt + 1 < NT) {
            if (kt + 2 < NT) asm volatile("s_waitcnt vmcnt(3)" ::: "memory");
            else             asm volatile("s_waitcnt vmcnt(0)" ::: "memory");
            __builtin_amdgcn_s_barrier();
        }
        sw = (sw == 2) ? 0 : sw + 1;
        sr = (sr == 2) ? 0 : sr + 1;
    }
#undef ST1
    int hi = lane >> 4;
#pragma unroll
    for (int nf = 0; nf < 4; nf++) {
        int col = n0 + wn * 64 + nf * 16 + fr;
        float bias = b1[col];
#pragma unroll
        for (int mf = 0; mf < 4; mf++) {
            int r0 = wm * 64 + mf * 16 + hi * 4;
#pragma unroll
            for (int r = 0; r < 4; r++) {
                float v = fmaxf(acc[mf][nf][r] + bias, 0.f);
                h[(size_t)(m0 + r0 + r) * HDIM + col] = f2bf(v);
            }
        }
    }
}

// gemm2y: yb[e][m][n] = wt[e][m] * (h[e][m] @ w2t[e][n] + b2[e][n])
__global__ __launch_bounds__(512, 4) void gemm2y_kernel(
    const unsigned short* __restrict__ h, const unsigned short* __restrict__ w2t,
    const float* __restrict__ b2, const float* __restrict__ wt_list,
    float* __restrict__ yb) {
    int bid = blockIdx.x;
    int e = bid & 7, idx = bid >> 3;          // 64 blocks per expert/XCD
    int m0 = (idx & 15) * 128, n0 = (idx >> 4) * 256;
    h       += (size_t)e * KCAP * HDIM;
    w2t     += (size_t)e * DDIM * HDIM;
    b2      += (size_t)e * DDIM;
    wt_list += (size_t)e * KCAP;
    yb      += (size_t)e * KCAP * DDIM;
    __shared__ unsigned short As[3 * ASLOT];
    __shared__ unsigned short Bs[3 * BSLOT];
    __shared__ float wts[128];
    int t = threadIdx.x;
    if (t < 128) wts[t] = wt_list[m0 + t];
    __syncthreads();
    int w = t >> 6, lane = t & 63, l4 = lane >> 2;
    unsigned swz = (unsigned)(((lane & 3) ^ ((lane >> 3) & 3)) << 4);
    const char* pa  = (const char*)(h + (size_t)(m0 + w * 16 + l4) * HDIM) + swz;
    const char* pb0 = (const char*)(w2t + (size_t)(n0 + w * 16 + l4) * HDIM) + swz;
    const char* pb1 = (const char*)(w2t + (size_t)(n0 + 128 + w * 16 + l4) * HDIM) + swz;
    unsigned short* da  = As + (w * 16) * 32;
    unsigned short* db0 = Bs + (w * 16) * 32;
    unsigned short* db1 = Bs + (128 + w * 16) * 32;
#define ST2(slot, koff) do {                                         \
    gl_lds16(pa  + (koff), da  + (slot) * ASLOT);                    \
    gl_lds16(pb0 + (koff), db0 + (slot) * BSLOT);                    \
    gl_lds16(pb1 + (koff), db1 + (slot) * BSLOT); } while (0)
    int wm = w >> 2, wn = w & 3;
    int fr = lane & 15, kg = lane >> 4;
    unsigned koffr = (unsigned)((kg ^ ((fr >> 1) & 3)) << 4);
    const int NT = HDIM / 32;   // 128
    f32x4 acc[4][4] = {};
    ST2(0, 0); ST2(1, 64);
    asm volatile("s_waitcnt vmcnt(3)" ::: "memory");
    __builtin_amdgcn_s_barrier();
    size_t ko = 128;
    int sw = 2, sr = 0;
    for (int kt = 0; kt < NT; kt++) {
        if (kt + 2 < NT) { ST2(sw, ko); ko += 64; }
        const char* ab = (const char*)As + sr * (ASLOT * 2);
        const char* bb = (const char*)Bs + sr * (BSLOT * 2);
        bf16x8 af[4], bf[4];
#pragma unroll
        for (int mf = 0; mf < 4; mf++)
            af[mf] = *(const bf16x8*)(ab + (wm * 64 + mf * 16 + fr) * 64 + koffr);
#pragma unroll
        for (int nf = 0; nf < 4; nf++)
            bf[nf] = *(const bf16x8*)(bb + (wn * 64 + nf * 16 + fr) * 64 + koffr);
        __builtin_amdgcn_s_setprio(1);
#pragma unroll
        for (int mf = 0; mf < 4; mf++)
#pragma unroll
            for (int nf = 0; nf < 4; nf++)
                acc[mf][nf] = __builtin_amdgcn_mfma_f32_16x16x32_bf16(
                    af[mf], bf[nf], acc[mf][nf], 0, 0, 0);
        __builtin_amdgcn_s_setprio(0);
        if (kt + 1 < NT) {
            if (kt + 2 < NT) asm volatile("s_waitcnt vmcnt(3)" ::: "memory");
            else             asm volatile("s_waitcnt vmcnt(0)" ::: "memory");
            __builtin_amdgcn_s_barrier();
        }
        sw = (sw == 2) ? 0 : sw + 1;
        sr = (sr == 2) ? 0 : sr + 1;
    }
#undef ST2
    int hi = lane >> 4;
#pragma unroll
    for (int nf = 0; nf < 4; nf++) {
        int col = n0 + wn * 64 + nf * 16 + fr;
        float bias = b2[col];
#pragma unroll
        for (int mf = 0; mf < 4; mf++) {
            int r0 = wm * 64 + mf * 16 + hi * 4;
#pragma unroll
            for (int r = 0; r < 4; r++) {
                int lrow = r0 + r;
                yb[(size_t)(m0 + lrow) * DDIM + col] = wts[lrow] * (acc[mf][nf][r] + bias);
            }
        }
    }
}

// ---------------- combine: out[b] = sum_e yb[e][inv[e][b]] ----------------
__global__ __launch_bounds__(256) void combine_kernel(
    const float* __restrict__ yb, const int* __restrict__ inv,
    float* __restrict__ out) {
    int b = blockIdx.x, t = threadIdx.x;
    float4 acc = {0.f, 0.f, 0.f, 0.f};
#pragma unroll
    for (int e = 0; e < NEXP; e++) {
        int s = inv[(size_t)e * BTOK + b];
        if (s >= 0) {
            float4 v = *(const float4*)(yb + ((size_t)e * KCAP + s) * DDIM + t * 4);
            acc.x += v.x; acc.y += v.y; acc.z += v.z; acc.w += v.w;
        }
    }
    *(float4*)(out + (size_t)b * DDIM + t * 4) = acc;
}

extern "C" void kernel_launch(void* const* d_in, const int* in_sizes, int n_in,
                              void* d_out, int out_size, void* d_ws, size_t ws_size,
                              hipStream_t stream) {
    const float* x  = (const float*)d_in[0];
    const float* Wr = (const float*)d_in[1];
    const float* br = (const float*)d_in[2];
    const float* W1 = (const float*)d_in[3];
    const float* b1 = (const float*)d_in[4];
    const float* W2 = (const float*)d_in[5];
    const float* b2 = (const float*)d_in[6];
    float* out = (float*)d_out;

    char* ws = (char*)d_ws;
    float*    gateT    = (float*)ws;                       // 256 KB
    unsigned* meta     = (unsigned*)(ws + 262144);         // cutoff[8], ngt[8]
    unsigned* cnt      = meta + 16;
    int*      idx_list = (int*)(ws + 327680);              // 64 KB
    float*    wt_list  = (float*)(ws + 393216);            // 64 KB
    int*      inv      = (int*)(ws + 458752);              // 256 KB
    unsigned short* xbuf = (unsigned short*)(ws + 1 * MB);    // 16 MB
    unsigned short* w1t  = (unsigned short*)(ws + 17 * MB);   // 64 MB
    unsigned short* w2t  = (unsigned short*)(ws + 81 * MB);   // 64 MB
    unsigned short* hbuf = (unsigned short*)(ws + 145 * MB);  // 128 MB
    float*          yb   = (float*)(ws + 273 * MB);           // 64 MB
    const size_t NEED = 337 * MB;
    if (ws_size < NEED) return;

    hipMemsetAsync(cnt, 0, NEXP * sizeof(unsigned), stream);
    hipMemsetAsync(inv, 0xFF, (size_t)NEXP * BTOK * sizeof(int), stream);

    router_kernel<<<dim3(BTOK / 4), 256, 0, stream>>>(x, Wr, br, gateT, xbuf);
    select_kernel<<<dim3(NEXP), 256, 0, stream>>>(gateT, meta);
    build_kernel<<<dim3(BTOK / 256, NEXP), 256, 0, stream>>>(gateT, meta, cnt, idx_list, wt_list);
    tie_kernel<<<dim3(NEXP), 256, 0, stream>>>(gateT, meta, cnt, idx_list, wt_list);

    tcvt_kernel<<<dim3(HDIM / 64, DDIM / 64, NEXP), 256, 0, stream>>>(W1, w1t, DDIM, HDIM);
    tcvt_kernel<<<dim3(DDIM / 64, HDIM / 64, NEXP), 256, 0, stream>>>(W2, w2t, HDIM, DDIM);
    invb_kernel<<<dim3(NEXP * KCAP / 256), 256, 0, stream>>>(idx_list, inv);

    // 1D grids, expert = bid&7 (expert-per-XCD swizzle)
    gemm1_kernel<<<dim3((KCAP / 128) * (HDIM / 256) * NEXP), 512, 0, stream>>>(
        xbuf, w1t, b1, idx_list, hbuf);
    gemm2y_kernel<<<dim3((KCAP / 128) * (DDIM / 256) * NEXP), 512, 0, stream>>>(
        hbuf, w2t, b2, wt_list, yb);
    combine_kernel<<<dim3(BTOK), 256, 0, stream>>>(yb, inv, out);
}